// Round 20
// baseline (244.787 us; speedup 1.0000x reference)
//
#include <hip/hip_runtime.h>

// k-th NN distance (k=32 -> 33rd smallest, self excluded), B=16384, D=128.
// R20: T15 retry without the spill — ping-pong accumulators via 2x unroll
// (even iter: MFMA->accA, filter accB; odd iter: MFMA->accB, filter accA).
// No accC->accP copy (R19's copy pushed live regs past the allocator's 64
// budget -> scratch spill -> +25MB WRITE, both pipes down). Counts/order
// bit-identical to R18/R5. Base: R18's verified 8-wave kernel (128.7us).

typedef unsigned short u16;
typedef unsigned int   u32;
typedef __attribute__((ext_vector_type(8))) u16    ushort8;
typedef __attribute__((ext_vector_type(8))) __bf16 bf16x8;
typedef __attribute__((ext_vector_type(4))) float  f32x4;
typedef __attribute__((ext_vector_type(4))) u32    u32x4;

#define NB   16384
#define ND   128
#define NSEG 32           // segments per row = 4 q * 2 wc * 4 lq
#define SCAP 12           // slots per segment (lambda~2.25)
#define NTH  33           // 33rd smallest
#define ZWH  (-2.62f)     // WH quantile z: p~0.0044 -> ~72 cands/row
#define NEGF (-3.0e38f)
#define POSF ( 3.0e38f)
#define NPB  64           // rows per prepstats block
#define NPBL 256          // prepstats grid

// ---- workspace layout (bytes), total ~31.5 MB ----
#define OFF_X    ((size_t)0)
#define OFF_NORM (OFF_X    + (size_t)NB * ND * 2)
#define OFF_TACC (OFF_NORM + (size_t)NB * 4)
#define OFF_PART (OFF_TACC + (size_t)NB * 4)
#define OFF_CNTS (OFF_PART + (size_t)NPBL * 130 * 4)
#define OFF_CAND (OFF_CNTS + (size_t)NB * NSEG * 4)

static __device__ __forceinline__ u16 f2bf(float f) {
  u32 u = __float_as_uint(f);
  u32 r = u + 0x7FFFu + ((u >> 16) & 1u);
  return (u16)(r >> 16);
}
static __device__ __forceinline__ float bf2f(u16 h) {
  return __uint_as_float(((u32)h) << 16);
}

#if defined(__has_builtin)
#if __has_builtin(__builtin_amdgcn_global_load_lds)
#define HAVE_GLDS 1
#endif
#endif

// Stage 16B/lane: LDS dest = wave-uniform base + lane*16 (linear).
static __device__ __forceinline__ void stage16(const u16* gsrc_lane,
                                               u16* lds_base, int l) {
#ifdef HAVE_GLDS
  __builtin_amdgcn_global_load_lds(
      (const __attribute__((address_space(1))) void*)gsrc_lane,
      (__attribute__((address_space(3))) void*)lds_base, 16, 0, 0);
#else
  *(ushort8*)(lds_base + l * 8) = *(const ushort8*)gsrc_lane;
#endif
}
// Stage 4B/lane (for the column-norm vector).
static __device__ __forceinline__ void stage4(const float* gsrc_lane,
                                              float* lds_base, int l) {
#ifdef HAVE_GLDS
  __builtin_amdgcn_global_load_lds(
      (const __attribute__((address_space(1))) void*)gsrc_lane,
      (__attribute__((address_space(3))) void*)lds_base, 4, 0, 0);
#else
  lds_base[l] = *gsrc_lane;
#endif
}

// ---------------- K1: fused bf16 convert + norms + stat partials ---------
__global__ void k_prepstats(const float* __restrict__ x, u16* __restrict__ X,
                            float* __restrict__ norms, float* __restrict__ partial) {
  __shared__ float xs[16][128];
  __shared__ float red1[256], red2[256];
  int t = threadIdx.x;
  int cg = t & 15;          // col-group: cols cg*8 .. cg*8+7
  int rs = t >> 4;          // row-sub 0..15
  int rbase = blockIdx.x * NPB;
  float cs[8] = {0.f, 0.f, 0.f, 0.f, 0.f, 0.f, 0.f, 0.f};
  float s1 = 0.f, s2 = 0.f;
#pragma unroll
  for (int rr = 0; rr < NPB / 16; ++rr) {
    int row = rbase + rs + rr * 16;
    const float* src = x + (size_t)row * ND + cg * 8;
    float4 a0 = *(const float4*)(src);
    float4 a1 = *(const float4*)(src + 4);
    float v[8] = {a0.x, a0.y, a0.z, a0.w, a1.x, a1.y, a1.z, a1.w};
    ushort8 pack;
    float ns = 0.f;
#pragma unroll
    for (int u = 0; u < 8; ++u) {
      u16 h = f2bf(v[u]);
      float b = bf2f(h);
      pack[u] = h;
      ns += b * b;
      cs[u] += b;
    }
    *(ushort8*)(X + (size_t)row * ND + cg * 8) = pack;
#pragma unroll
    for (int off = 1; off < 16; off <<= 1) ns += __shfl_xor(ns, off, 64);
    if (cg == 0) { norms[row] = ns; s1 += ns; s2 += ns * ns; }
  }
#pragma unroll
  for (int u = 0; u < 8; ++u) xs[rs][cg * 8 + u] = cs[u];
  red1[t] = s1; red2[t] = s2;
  __syncthreads();
  if (t < 128) {
    float a = 0.f;
    for (int r2 = 0; r2 < 16; ++r2) a += xs[r2][t];
    partial[(size_t)blockIdx.x * 130 + t] = a;
  }
  for (int st = 128; st > 0; st >>= 1) {
    if (t < st) { red1[t] += red1[t + st]; red2[t] += red2[t + st]; }
    __syncthreads();
  }
  if (t == 0) {
    partial[(size_t)blockIdx.x * 130 + 128] = red1[0];
    partial[(size_t)blockIdx.x * 130 + 129] = red2[0];
  }
}

// ---------------- K2: per-row threshold via Wilson-Hilferty chi^2 --------
__global__ void k_thresh(const u16* __restrict__ X, const float* __restrict__ norms,
                         const float* __restrict__ partial, float* __restrict__ tacc) {
  __shared__ float xb[128];
  __shared__ float ssum[2];
  int t = threadIdx.x;
  if (t < 128) {
    float a = 0.f;
    for (int b = 0; b < NPBL; ++b) a += partial[(size_t)b * 130 + t];
    xb[t] = a * (1.0f / NB);
  } else if (t == 128 || t == 129) {
    float a = 0.f;
    for (int b = 0; b < NPBL; ++b) a += partial[(size_t)b * 130 + t];
    ssum[t - 128] = a;
  }
  __syncthreads();
  int r = blockIdx.x * 256 + t;  // grid 64
  float n = norms[r];
  const u16* xr = X + (size_t)r * ND;
  float dot = 0.f;
#pragma unroll
  for (int c8 = 0; c8 < 16; ++c8) {
    ushort8 v = *(const ushort8*)(xr + c8 * 8);
#pragma unroll
    for (int j = 0; j < 8; ++j) dot += bf2f(v[j]) * xb[c8 * 8 + j];
  }
  float nbar = ssum[0] * (1.0f / NB);
  float Vn = fmaxf(ssum[1] * (1.0f / NB) - nbar * nbar, 0.f);
  float m = n + nbar - 2.f * dot;             // exact E_j[sq_rj]
  float v = Vn + 4.f * n * (nbar / ND);       // Var_j[sq_rj] model
  float nu = 2.f * m * m / v;
  float cc = v / (2.f * m);
  float a1 = 2.f / (9.f * nu);
  float inner = 1.f - a1 + ZWH * sqrtf(a1);
  float tsq = cc * nu * inner * inner * inner;
  tacc[r] = 0.5f * (n - tsq);   // val = acc - nc/2 >= tacc  <=>  sq <= tsq
}

// Stage tile (IT) into buffer BUF; norms into ring slot (IT)&3.
#define STAGE_TILE(IT, BUF)                                                   \
  {                                                                           \
    const int cs_ = q * 4096 + (IT) * 128;                                    \
    u16* dst_ = ldsA[BUF];                                                    \
    _Pragma("unroll") for (int s = 0; s < 4; ++s) {                           \
      int g = w * 4 + s;                                                      \
      stage16(X + (size_t)(cs_ + (g & 7) * 16 + lm) * ND + (g >> 3) * 32 + koff, \
              &dst_[g * 512], l);                                             \
    }                                                                         \
    if (w < 2) stage4(norms + cs_ + w * 64 + l, &nchs[(IT) & 3][w * 64], l);  \
  }

// MFMA tile from buffer BUF into ACC (zero-init).
#define MFMA_TILE(ACC, BUF)                                                   \
  {                                                                           \
    _Pragma("unroll") for (int i = 0; i < 4; ++i)                             \
      _Pragma("unroll") for (int j = 0; j < 2; ++j)                           \
        (ACC)[i][j] = (f32x4){0.f, 0.f, 0.f, 0.f};                            \
    const u16* srcA_ = ldsA[BUF];                                             \
    _Pragma("unroll") for (int k = 0; k < 4; ++k) {                           \
      bf16x8 af[4];                                                           \
      _Pragma("unroll") for (int i = 0; i < 4; ++i)                           \
        af[i] = __builtin_bit_cast(bf16x8,                                    \
                 *(const ushort8*)(&srcA_[(k * 8 + wc * 4 + i) * 512 + l * 8])); \
      _Pragma("unroll") for (int i = 0; i < 4; ++i)                           \
        _Pragma("unroll") for (int j = 0; j < 2; ++j)                         \
          (ACC)[i][j] = __builtin_amdgcn_mfma_f32_16x16x32_bf16(af[i], bfrag[k][j], (ACC)[i][j], 0, 0, 0); \
  } }

// Filter accumulator ACC of iter ITF (reads ring slot ITF&3).
#define FILTER_IT(ACC, ITF)                                                   \
  {                                                                           \
    const int c0f = q * 4096 + (ITF) * 128;                                   \
    const bool dgf = (c0f == r0);                                             \
    f32x4 nch4[4];                                                            \
    _Pragma("unroll") for (int i = 0; i < 4; ++i) {                           \
      nch4[i] = *(const f32x4*)(&nchs[(ITF) & 3][wc * 64 + i * 16 + lq * 4]); \
      nch4[i] = nch4[i] * 0.5f;                                               \
    }                                                                         \
    _Pragma("unroll") for (int i = 0; i < 4; ++i) {                           \
      _Pragma("unroll") for (int j = 0; j < 2; ++j) {                         \
        _Pragma("unroll") for (int v = 0; v < 4; ++v) {                       \
          float val = (ACC)[i][j][v] - nch4[i][v];                            \
          bool p = (val >= tj[j]);                                            \
          if (dgf) p = p && ((c0f + wc * 64 + i * 16 + lq * 4 + v) != rj[j]); \
          if (p) {                                                            \
            u32 c = cnt2[j];                                                  \
            if (c < SCAP) cands[segb[j] + c] = val;                           \
            cnt2[j] = c + 1;                                                  \
          }                                                                   \
        }                                                                     \
      }                                                                       \
    }                                                                         \
  }

// ---------------- K3: MFMA gram, 8-wave + ping-pong filter overlap -------
// 512 blocks = 128 strips x 4 quarters (XCD-chunked). 8 waves (512 thr):
// (wr=w>>1) x (wc=w&1); wave = 32 rows x 64 cols. Even iter: MFMA->accA,
// filter accB (iter-1); odd iter: MFMA->accB, filter accA. No acc copy.
__global__ __launch_bounds__(512, 4) void k_gram(
    const u16* __restrict__ X, const float* __restrict__ norms,
    const float* __restrict__ tacc, u32* __restrict__ counts,
    float* __restrict__ cands) {
  __shared__ u16 ldsA[2][32 * 512];            // 2 x 32KB
  __shared__ __align__(16) float nchs[4][128]; // 4-slot ring
  const int bid = blockIdx.x;
  const int logical = (bid & 7) * 64 + (bid >> 3);   // XCD-chunked, bijective
  const int q = logical >> 7, strip = logical & 127;
  const int r0 = strip * 128;
  const int t = threadIdx.x, w = t >> 6, l = t & 63;
  const int wr = w >> 1, wc = w & 1;
  const int lm = l & 15, lq = l >> 4;
  const int koff = lq * 8;

  // B fragments (wave's 32 rows) -> registers, loaded once.
  bf16x8 bfrag[4][2];  // [k][j]
#pragma unroll
  for (int k = 0; k < 4; ++k)
#pragma unroll
    for (int j = 0; j < 2; ++j)
      bfrag[k][j] = __builtin_bit_cast(bf16x8, *(const ushort8*)(
          X + (size_t)(r0 + wr * 32 + j * 16 + lm) * ND + k * 32 + koff));

  int rj[2]; float tj[2]; u32 cnt2[2]; u32 segb[2];
#pragma unroll
  for (int j = 0; j < 2; ++j) {
    rj[j] = r0 + wr * 32 + j * 16 + lm;
    tj[j] = tacc[rj[j]];
    cnt2[j] = 0;
    segb[j] = (u32)(rj[j] * NSEG + q * 8 + wc * 4 + lq) * SCAP;
  }

  // prologue: stage tile 0 into buffer 0, norms ring slot 0
  STAGE_TILE(0, 0)
  __syncthreads();

  f32x4 accA[4][2], accB[4][2];

  for (int itp = 0; itp < 16; ++itp) {
    const int itE = 2 * itp, itO = itE + 1;
    // ---- even iter: compute accA from buf0; filter accB (iter itE-1) ----
    STAGE_TILE(itO, 1)
    __builtin_amdgcn_sched_barrier(0);
    MFMA_TILE(accA, 0)
    if (itp > 0) { FILTER_IT(accB, itE - 1) }
    __syncthreads();
    // ---- odd iter: compute accB from buf1; filter accA (iter itE) -------
    if (itO + 1 < 32) STAGE_TILE(itO + 1, 0)
    __builtin_amdgcn_sched_barrier(0);
    MFMA_TILE(accB, 1)
    FILTER_IT(accA, itE)
    __syncthreads();
  }

  // epilogue: filter accB of iter 31 (ring slot 3 still valid)
  FILTER_IT(accB, 31)

#pragma unroll
  for (int j = 0; j < 2; ++j)
    counts[rj[j] * NSEG + q * 8 + wc * 4 + lq] = cnt2[j];
}

// ---------------- K4: per-row exact 33rd smallest among candidates --------
__global__ void k_select(const u32* __restrict__ counts, const float* __restrict__ cands,
                         const float* __restrict__ norms, float* __restrict__ out) {
  int w = threadIdx.x >> 6, l = threadIdx.x & 63;
  int r = blockIdx.x * 4 + w;  // grid 4096
  u32 myc = (l < NSEG) ? counts[r * NSEG + l] : 0u;
  u32 tot = myc, mx = myc;
#pragma unroll
  for (int off = 1; off < 64; off <<= 1) {
    tot += __shfl_xor(tot, off, 64);
    u32 o = (u32)__shfl_xor((int)mx, off, 64);
    mx = mx > o ? mx : o;
  }
  if (tot < NTH || mx > SCAP) return;  // fallback kernel owns this row

  const float* base = cands + (size_t)r * (NSEG * SCAP);
  float v0, v1, v2, v3, v4, v5;
#define LOADV(e, dst)                                        \
  {                                                          \
    int f = l + 64 * e;                                      \
    int sg = f / SCAP, sl = f - sg * SCAP;                   \
    u32 c = (u32)__shfl((int)myc, sg, 64);                   \
    float x = base[f];                                       \
    dst = (sl < (int)c) ? x : NEGF;                          \
  }
  LOADV(0, v0) LOADV(1, v1) LOADV(2, v2) LOADV(3, v3) LOADV(4, v4) LOADV(5, v5)
#undef LOADV

  float last = NEGF;
  for (int e = 0; e < NTH; ++e) {  // bigger val = closer; extract-max x33
    float m = fmaxf(fmaxf(fmaxf(v0, v1), fmaxf(v2, v3)), fmaxf(v4, v5));
#pragma unroll
    for (int off = 1; off < 64; off <<= 1) m = fmaxf(m, __shfl_xor(m, off, 64));
    bool mine = (v0 == m) || (v1 == m) || (v2 == m) || (v3 == m) || (v4 == m) || (v5 == m);
    unsigned long long bal = __ballot(mine);
    int owner = __ffsll(bal) - 1;
    if (l == owner) {
      if      (v0 == m) v0 = NEGF;
      else if (v1 == m) v1 = NEGF;
      else if (v2 == m) v2 = NEGF;
      else if (v3 == m) v3 = NEGF;
      else if (v4 == m) v4 = NEGF;
      else              v5 = NEGF;
    }
    last = m;
  }
  out[r] = sqrtf(fmaxf(norms[r] - 2.f * last, 0.f));  // sq = n_r - 2*val
}

// ---------------- K5: exact brute-force fallback (expected ~0 rows) -------
__global__ void k_fallback(const u32* __restrict__ counts, const u16* __restrict__ X,
                           const float* __restrict__ norms, float* __restrict__ out) {
  __shared__ float sq[NB];     // 64 KB
  __shared__ float xr[ND];
  __shared__ float rmin[256];
  __shared__ int   ridx[256];
  __shared__ float tmin[256];
  __shared__ int   tidx[256];
  __shared__ int   nbad;
  __shared__ int   badlist[256];
  int t = threadIdx.x;
  if (t == 0) nbad = 0;
  __syncthreads();
  int r = blockIdx.x * 256 + t;   // grid 64: covers NB exactly
  u32 tot = 0, mx = 0;
#pragma unroll
  for (int s4 = 0; s4 < 8; ++s4) {
    u32x4 c = *(const u32x4*)(counts + (size_t)r * NSEG + s4 * 4);
#pragma unroll
    for (int u = 0; u < 4; ++u) { tot += c[u]; mx = c[u] > mx ? c[u] : mx; }
  }
  if (tot < NTH || mx > SCAP) { int p = atomicAdd(&nbad, 1); badlist[p] = r; }
  __syncthreads();
  int nb = nbad;
  for (int ii = 0; ii < nb; ++ii) {
    int rr = badlist[ii];
    if (t < 128) xr[t] = bf2f(X[(size_t)rr * ND + t]);
    __syncthreads();
    float n_r = norms[rr];
    for (int jj = 0; jj < 64; ++jj) {
      int j = t + 256 * jj;
      const u16* xj = X + (size_t)j * ND;
      float dot = 0.f;
#pragma unroll
      for (int c8 = 0; c8 < 16; ++c8) {
        ushort8 vv = *(const ushort8*)(xj + c8 * 8);
#pragma unroll
        for (int u = 0; u < 8; ++u) dot += bf2f(vv[u]) * xr[c8 * 8 + u];
      }
      sq[j] = (j == rr) ? POSF : fmaxf(n_r + norms[j] - 2.f * dot, 0.f);
    }
    __syncthreads();
    {
      float lmv = POSF; int lix = -1;
      for (int jj = 0; jj < 64; ++jj) {
        int j = t + 256 * jj;
        float s = sq[j];
        if (s < lmv) { lmv = s; lix = j; }
      }
      rmin[t] = lmv; ridx[t] = lix;
    }
    __syncthreads();
    float last = 0.f;
    for (int e = 0; e < NTH; ++e) {
      tmin[t] = rmin[t]; tidx[t] = ridx[t];
      __syncthreads();
      for (int s = 128; s > 0; s >>= 1) {
        if (t < s && tmin[t + s] < tmin[t]) { tmin[t] = tmin[t + s]; tidx[t] = tidx[t + s]; }
        __syncthreads();
      }
      float gm = tmin[0]; int gi = tidx[0];
      last = gm;
      __syncthreads();
      if (t == (gi & 255)) {         // owner clears and rescans its stripe
        sq[gi] = POSF;
        float lmv = POSF; int lix = -1;
        for (int jj = 0; jj < 64; ++jj) {
          int j = t + 256 * jj;
          float s = sq[j];
          if (s < lmv) { lmv = s; lix = j; }
        }
        rmin[t] = lmv; ridx[t] = lix;
      }
      __syncthreads();
    }
    if (t == 0) out[rr] = sqrtf(fmaxf(last, 0.f));
    __syncthreads();
  }
}

extern "C" void kernel_launch(void* const* d_in, const int* in_sizes, int n_in,
                              void* d_out, int out_size, void* d_ws, size_t ws_size,
                              hipStream_t stream) {
  const float* x = (const float*)d_in[0];
  float* out = (float*)d_out;
  char* ws = (char*)d_ws;
  u16*   X     = (u16*)  (ws + OFF_X);
  float* norms = (float*)(ws + OFF_NORM);
  float* tacc  = (float*)(ws + OFF_TACC);
  float* part  = (float*)(ws + OFF_PART);
  u32*   cnts  = (u32*)  (ws + OFF_CNTS);
  float* cands = (float*)(ws + OFF_CAND);

  k_prepstats<<<NPBL, 256, 0, stream>>>(x, X, norms, part);
  k_thresh   <<<64,   256, 0, stream>>>(X, norms, part, tacc);
  k_gram     <<<512,  512, 0, stream>>>(X, norms, tacc, cnts, cands);
  k_select   <<<4096, 256, 0, stream>>>(cnts, cands, norms, out);
  k_fallback <<<64,   256, 0, stream>>>(cnts, X, norms, out);
}

// Round 21
// 204.012 us; speedup vs baseline: 1.1999x; 1.1999x over previous
//
#include <hip/hip_runtime.h>

// k-th NN distance (k=32 -> 33rd smallest, self excluded), B=16384, D=128.
// R21: register-neutral filter/MFMA overlap — i-outer loop: per row-quad i,
// {4 ds_reads, 8 MFMAs, filter acc[i]}; filter(i) VALU issues while
// MFMA(i+1) executes. No second accumulator (R19/R20 both spilled at the
// 512-thread 64-VGPR budget: WRITE 352MB). Norms read direct from global
// (L1-resident) — nchs LDS ring and stage4 removed. Candidate order/count
// bit-identical to R18/R5. Base: R18 verified (k_gram 128.7us, total 181.5).

typedef unsigned short u16;
typedef unsigned int   u32;
typedef __attribute__((ext_vector_type(8))) u16    ushort8;
typedef __attribute__((ext_vector_type(8))) __bf16 bf16x8;
typedef __attribute__((ext_vector_type(4))) float  f32x4;
typedef __attribute__((ext_vector_type(4))) u32    u32x4;

#define NB   16384
#define ND   128
#define NSEG 32           // segments per row = 4 q * 2 wc * 4 lq
#define SCAP 12           // slots per segment (lambda~2.25)
#define NTH  33           // 33rd smallest
#define ZWH  (-2.62f)     // WH quantile z: p~0.0044 -> ~72 cands/row
#define NEGF (-3.0e38f)
#define POSF ( 3.0e38f)
#define NPB  64           // rows per prepstats block
#define NPBL 256          // prepstats grid

// ---- workspace layout (bytes), total ~31.5 MB ----
#define OFF_X    ((size_t)0)
#define OFF_NORM (OFF_X    + (size_t)NB * ND * 2)
#define OFF_TACC (OFF_NORM + (size_t)NB * 4)
#define OFF_PART (OFF_TACC + (size_t)NB * 4)
#define OFF_CNTS (OFF_PART + (size_t)NPBL * 130 * 4)
#define OFF_CAND (OFF_CNTS + (size_t)NB * NSEG * 4)

static __device__ __forceinline__ u16 f2bf(float f) {
  u32 u = __float_as_uint(f);
  u32 r = u + 0x7FFFu + ((u >> 16) & 1u);
  return (u16)(r >> 16);
}
static __device__ __forceinline__ float bf2f(u16 h) {
  return __uint_as_float(((u32)h) << 16);
}

#if defined(__has_builtin)
#if __has_builtin(__builtin_amdgcn_global_load_lds)
#define HAVE_GLDS 1
#endif
#endif

// Stage 16B/lane: LDS dest = wave-uniform base + lane*16 (linear).
static __device__ __forceinline__ void stage16(const u16* gsrc_lane,
                                               u16* lds_base, int l) {
#ifdef HAVE_GLDS
  __builtin_amdgcn_global_load_lds(
      (const __attribute__((address_space(1))) void*)gsrc_lane,
      (__attribute__((address_space(3))) void*)lds_base, 16, 0, 0);
#else
  *(ushort8*)(lds_base + l * 8) = *(const ushort8*)gsrc_lane;
#endif
}

// ---------------- K1: fused bf16 convert + norms + stat partials ---------
__global__ void k_prepstats(const float* __restrict__ x, u16* __restrict__ X,
                            float* __restrict__ norms, float* __restrict__ partial) {
  __shared__ float xs[16][128];
  __shared__ float red1[256], red2[256];
  int t = threadIdx.x;
  int cg = t & 15;          // col-group: cols cg*8 .. cg*8+7
  int rs = t >> 4;          // row-sub 0..15
  int rbase = blockIdx.x * NPB;
  float cs[8] = {0.f, 0.f, 0.f, 0.f, 0.f, 0.f, 0.f, 0.f};
  float s1 = 0.f, s2 = 0.f;
#pragma unroll
  for (int rr = 0; rr < NPB / 16; ++rr) {
    int row = rbase + rs + rr * 16;
    const float* src = x + (size_t)row * ND + cg * 8;
    float4 a0 = *(const float4*)(src);
    float4 a1 = *(const float4*)(src + 4);
    float v[8] = {a0.x, a0.y, a0.z, a0.w, a1.x, a1.y, a1.z, a1.w};
    ushort8 pack;
    float ns = 0.f;
#pragma unroll
    for (int u = 0; u < 8; ++u) {
      u16 h = f2bf(v[u]);
      float b = bf2f(h);
      pack[u] = h;
      ns += b * b;
      cs[u] += b;
    }
    *(ushort8*)(X + (size_t)row * ND + cg * 8) = pack;
#pragma unroll
    for (int off = 1; off < 16; off <<= 1) ns += __shfl_xor(ns, off, 64);
    if (cg == 0) { norms[row] = ns; s1 += ns; s2 += ns * ns; }
  }
#pragma unroll
  for (int u = 0; u < 8; ++u) xs[rs][cg * 8 + u] = cs[u];
  red1[t] = s1; red2[t] = s2;
  __syncthreads();
  if (t < 128) {
    float a = 0.f;
    for (int r2 = 0; r2 < 16; ++r2) a += xs[r2][t];
    partial[(size_t)blockIdx.x * 130 + t] = a;
  }
  for (int st = 128; st > 0; st >>= 1) {
    if (t < st) { red1[t] += red1[t + st]; red2[t] += red2[t + st]; }
    __syncthreads();
  }
  if (t == 0) {
    partial[(size_t)blockIdx.x * 130 + 128] = red1[0];
    partial[(size_t)blockIdx.x * 130 + 129] = red2[0];
  }
}

// ---------------- K2: per-row threshold via Wilson-Hilferty chi^2 --------
__global__ void k_thresh(const u16* __restrict__ X, const float* __restrict__ norms,
                         const float* __restrict__ partial, float* __restrict__ tacc) {
  __shared__ float xb[128];
  __shared__ float ssum[2];
  int t = threadIdx.x;
  if (t < 128) {
    float a = 0.f;
    for (int b = 0; b < NPBL; ++b) a += partial[(size_t)b * 130 + t];
    xb[t] = a * (1.0f / NB);
  } else if (t == 128 || t == 129) {
    float a = 0.f;
    for (int b = 0; b < NPBL; ++b) a += partial[(size_t)b * 130 + t];
    ssum[t - 128] = a;
  }
  __syncthreads();
  int r = blockIdx.x * 256 + t;  // grid 64
  float n = norms[r];
  const u16* xr = X + (size_t)r * ND;
  float dot = 0.f;
#pragma unroll
  for (int c8 = 0; c8 < 16; ++c8) {
    ushort8 v = *(const ushort8*)(xr + c8 * 8);
#pragma unroll
    for (int j = 0; j < 8; ++j) dot += bf2f(v[j]) * xb[c8 * 8 + j];
  }
  float nbar = ssum[0] * (1.0f / NB);
  float Vn = fmaxf(ssum[1] * (1.0f / NB) - nbar * nbar, 0.f);
  float m = n + nbar - 2.f * dot;             // exact E_j[sq_rj]
  float v = Vn + 4.f * n * (nbar / ND);       // Var_j[sq_rj] model
  float nu = 2.f * m * m / v;
  float cc = v / (2.f * m);
  float a1 = 2.f / (9.f * nu);
  float inner = 1.f - a1 + ZWH * sqrtf(a1);
  float tsq = cc * nu * inner * inner * inner;
  tacc[r] = 0.5f * (n - tsq);   // val = acc - nc/2 >= tacc  <=>  sq <= tsq
}

// ---------------- K3: MFMA gram, 8-wave, i-outer filter overlap ----------
// 512 blocks = 128 strips x 4 quarters (XCD-chunked). 8 waves (512 thr):
// (wr=w>>1) x (wc=w&1); wave = 32 rows x 64 cols of the 128x128 iter tile.
// Per row-quad i: 4 ds_reads + 8 MFMAs + filter(i) — filter(i)'s VALU
// overlaps MFMA(i+1). Norms loaded direct from global (L1-resident).
__global__ __launch_bounds__(512, 4) void k_gram(
    const u16* __restrict__ X, const float* __restrict__ norms,
    const float* __restrict__ tacc, u32* __restrict__ counts,
    float* __restrict__ cands) {
  __shared__ u16 ldsA[2][32 * 512];            // 2 x 32KB
  const int bid = blockIdx.x;
  const int logical = (bid & 7) * 64 + (bid >> 3);   // XCD-chunked, bijective
  const int q = logical >> 7, strip = logical & 127;
  const int r0 = strip * 128;
  const int t = threadIdx.x, w = t >> 6, l = t & 63;
  const int wr = w >> 1, wc = w & 1;
  const int lm = l & 15, lq = l >> 4;
  const int koff = lq * 8;

  // B fragments (wave's 32 rows) -> registers, loaded once.
  bf16x8 bfrag[4][2];  // [k][j]
#pragma unroll
  for (int k = 0; k < 4; ++k)
#pragma unroll
    for (int j = 0; j < 2; ++j)
      bfrag[k][j] = __builtin_bit_cast(bf16x8, *(const ushort8*)(
          X + (size_t)(r0 + wr * 32 + j * 16 + lm) * ND + k * 32 + koff));

  int rj[2]; float tj[2]; u32 cnt2[2]; u32 segb[2];
#pragma unroll
  for (int j = 0; j < 2; ++j) {
    rj[j] = r0 + wr * 32 + j * 16 + lm;
    tj[j] = tacc[rj[j]];
    cnt2[j] = 0;
    segb[j] = (u32)(rj[j] * NSEG + q * 8 + wc * 4 + lq) * SCAP;
  }

  // prologue: stage tile 0 into buffer 0
  {
    const int c0 = q * 4096;
#pragma unroll
    for (int s = 0; s < 4; ++s) {
      int g = w * 4 + s;                 // e16 = g&7, k-chunk = g>>3
      stage16(X + (size_t)(c0 + (g & 7) * 16 + lm) * ND + (g >> 3) * 32 + koff,
              &ldsA[0][g * 512], l);
    }
  }
  __syncthreads();

  for (int it = 0; it < 32; ++it) {
    const int cur = it & 1;
    const int c0 = q * 4096 + it * 128;
    // issue next-tile staging FIRST (into the other buffer)
    if (it + 1 < 32) {
      const int c1 = c0 + 128;
      u16* dstA = ldsA[cur ^ 1];
#pragma unroll
      for (int s = 0; s < 4; ++s) {
        int g = w * 4 + s;
        stage16(X + (size_t)(c1 + (g & 7) * 16 + lm) * ND + (g >> 3) * 32 + koff,
                &dstA[g * 512], l);
      }
    }
    __builtin_amdgcn_sched_barrier(0);  // pin staging issue before compute

    const u16* srcA = ldsA[cur];
    const bool dg = (c0 == r0);

#pragma unroll
    for (int i = 0; i < 4; ++i) {
      // issue norm load early (L1-resident; consumed after i's MFMAs)
      f32x4 nch = *(const f32x4*)(norms + c0 + wc * 64 + i * 16 + lq * 4);
      // 4 ds_reads for this row-quad
      bf16x8 af[4];
#pragma unroll
      for (int k = 0; k < 4; ++k)
        af[k] = __builtin_bit_cast(bf16x8,
                 *(const ushort8*)(&srcA[(k * 8 + wc * 4 + i) * 512 + l * 8]));
      // 8 MFMAs for this row-quad
      f32x4 acc[2];
#pragma unroll
      for (int j = 0; j < 2; ++j) acc[j] = (f32x4){0.f, 0.f, 0.f, 0.f};
#pragma unroll
      for (int k = 0; k < 4; ++k)
#pragma unroll
        for (int j = 0; j < 2; ++j)
          acc[j] = __builtin_amdgcn_mfma_f32_16x16x32_bf16(af[k], bfrag[k][j], acc[j], 0, 0, 0);
      // filter(i): overlaps MFMA(i+1)'s execution
      nch = nch * 0.5f;
#pragma unroll
      for (int j = 0; j < 2; ++j) {
#pragma unroll
        for (int v = 0; v < 4; ++v) {
          float val = acc[j][v] - nch[v];        // = x_c.x_r - n_c/2
          bool p = (val >= tj[j]);
          if (dg) p = p && ((c0 + wc * 64 + i * 16 + lq * 4 + v) != rj[j]);
          if (p) {
            u32 c = cnt2[j];
            if (c < SCAP) cands[segb[j] + c] = val;
            cnt2[j] = c + 1;   // count past cap -> overflow detect
          }
        }
      }
    }

    __syncthreads();  // drains vmcnt(0): next tile staged; cur readers done
  }
#pragma unroll
  for (int j = 0; j < 2; ++j)
    counts[rj[j] * NSEG + q * 8 + wc * 4 + lq] = cnt2[j];
}

// ---------------- K4: per-row exact 33rd smallest among candidates --------
__global__ void k_select(const u32* __restrict__ counts, const float* __restrict__ cands,
                         const float* __restrict__ norms, float* __restrict__ out) {
  int w = threadIdx.x >> 6, l = threadIdx.x & 63;
  int r = blockIdx.x * 4 + w;  // grid 4096
  u32 myc = (l < NSEG) ? counts[r * NSEG + l] : 0u;
  u32 tot = myc, mx = myc;
#pragma unroll
  for (int off = 1; off < 64; off <<= 1) {
    tot += __shfl_xor(tot, off, 64);
    u32 o = (u32)__shfl_xor((int)mx, off, 64);
    mx = mx > o ? mx : o;
  }
  if (tot < NTH || mx > SCAP) return;  // fallback kernel owns this row

  const float* base = cands + (size_t)r * (NSEG * SCAP);
  float v0, v1, v2, v3, v4, v5;
#define LOADV(e, dst)                                        \
  {                                                          \
    int f = l + 64 * e;                                      \
    int sg = f / SCAP, sl = f - sg * SCAP;                   \
    u32 c = (u32)__shfl((int)myc, sg, 64);                   \
    float x = base[f];                                       \
    dst = (sl < (int)c) ? x : NEGF;                          \
  }
  LOADV(0, v0) LOADV(1, v1) LOADV(2, v2) LOADV(3, v3) LOADV(4, v4) LOADV(5, v5)
#undef LOADV

  float last = NEGF;
  for (int e = 0; e < NTH; ++e) {  // bigger val = closer; extract-max x33
    float m = fmaxf(fmaxf(fmaxf(v0, v1), fmaxf(v2, v3)), fmaxf(v4, v5));
#pragma unroll
    for (int off = 1; off < 64; off <<= 1) m = fmaxf(m, __shfl_xor(m, off, 64));
    bool mine = (v0 == m) || (v1 == m) || (v2 == m) || (v3 == m) || (v4 == m) || (v5 == m);
    unsigned long long bal = __ballot(mine);
    int owner = __ffsll(bal) - 1;
    if (l == owner) {
      if      (v0 == m) v0 = NEGF;
      else if (v1 == m) v1 = NEGF;
      else if (v2 == m) v2 = NEGF;
      else if (v3 == m) v3 = NEGF;
      else if (v4 == m) v4 = NEGF;
      else              v5 = NEGF;
    }
    last = m;
  }
  out[r] = sqrtf(fmaxf(norms[r] - 2.f * last, 0.f));  // sq = n_r - 2*val
}

// ---------------- K5: exact brute-force fallback (expected ~0 rows) -------
__global__ void k_fallback(const u32* __restrict__ counts, const u16* __restrict__ X,
                           const float* __restrict__ norms, float* __restrict__ out) {
  __shared__ float sq[NB];     // 64 KB
  __shared__ float xr[ND];
  __shared__ float rmin[256];
  __shared__ int   ridx[256];
  __shared__ float tmin[256];
  __shared__ int   tidx[256];
  __shared__ int   nbad;
  __shared__ int   badlist[256];
  int t = threadIdx.x;
  if (t == 0) nbad = 0;
  __syncthreads();
  int r = blockIdx.x * 256 + t;   // grid 64: covers NB exactly
  u32 tot = 0, mx = 0;
#pragma unroll
  for (int s4 = 0; s4 < 8; ++s4) {
    u32x4 c = *(const u32x4*)(counts + (size_t)r * NSEG + s4 * 4);
#pragma unroll
    for (int u = 0; u < 4; ++u) { tot += c[u]; mx = c[u] > mx ? c[u] : mx; }
  }
  if (tot < NTH || mx > SCAP) { int p = atomicAdd(&nbad, 1); badlist[p] = r; }
  __syncthreads();
  int nb = nbad;
  for (int ii = 0; ii < nb; ++ii) {
    int rr = badlist[ii];
    if (t < 128) xr[t] = bf2f(X[(size_t)rr * ND + t]);
    __syncthreads();
    float n_r = norms[rr];
    for (int jj = 0; jj < 64; ++jj) {
      int j = t + 256 * jj;
      const u16* xj = X + (size_t)j * ND;
      float dot = 0.f;
#pragma unroll
      for (int c8 = 0; c8 < 16; ++c8) {
        ushort8 vv = *(const ushort8*)(xj + c8 * 8);
#pragma unroll
        for (int u = 0; u < 8; ++u) dot += bf2f(vv[u]) * xr[c8 * 8 + u];
      }
      sq[j] = (j == rr) ? POSF : fmaxf(n_r + norms[j] - 2.f * dot, 0.f);
    }
    __syncthreads();
    {
      float lmv = POSF; int lix = -1;
      for (int jj = 0; jj < 64; ++jj) {
        int j = t + 256 * jj;
        float s = sq[j];
        if (s < lmv) { lmv = s; lix = j; }
      }
      rmin[t] = lmv; ridx[t] = lix;
    }
    __syncthreads();
    float last = 0.f;
    for (int e = 0; e < NTH; ++e) {
      tmin[t] = rmin[t]; tidx[t] = ridx[t];
      __syncthreads();
      for (int s = 128; s > 0; s >>= 1) {
        if (t < s && tmin[t + s] < tmin[t]) { tmin[t] = tmin[t + s]; tidx[t] = tidx[t + s]; }
        __syncthreads();
      }
      float gm = tmin[0]; int gi = tidx[0];
      last = gm;
      __syncthreads();
      if (t == (gi & 255)) {         // owner clears and rescans its stripe
        sq[gi] = POSF;
        float lmv = POSF; int lix = -1;
        for (int jj = 0; jj < 64; ++jj) {
          int j = t + 256 * jj;
          float s = sq[j];
          if (s < lmv) { lmv = s; lix = j; }
        }
        rmin[t] = lmv; ridx[t] = lix;
      }
      __syncthreads();
    }
    if (t == 0) out[rr] = sqrtf(fmaxf(last, 0.f));
    __syncthreads();
  }
}

extern "C" void kernel_launch(void* const* d_in, const int* in_sizes, int n_in,
                              void* d_out, int out_size, void* d_ws, size_t ws_size,
                              hipStream_t stream) {
  const float* x = (const float*)d_in[0];
  float* out = (float*)d_out;
  char* ws = (char*)d_ws;
  u16*   X     = (u16*)  (ws + OFF_X);
  float* norms = (float*)(ws + OFF_NORM);
  float* tacc  = (float*)(ws + OFF_TACC);
  float* part  = (float*)(ws + OFF_PART);
  u32*   cnts  = (u32*)  (ws + OFF_CNTS);
  float* cands = (float*)(ws + OFF_CAND);

  k_prepstats<<<NPBL, 256, 0, stream>>>(x, X, norms, part);
  k_thresh   <<<64,   256, 0, stream>>>(X, norms, part, tacc);
  k_gram     <<<512,  512, 0, stream>>>(X, norms, tacc, cnts, cands);
  k_select   <<<4096, 256, 0, stream>>>(cnts, cands, norms, out);
  k_fallback <<<64,   256, 0, stream>>>(cnts, X, norms, out);
}

// Round 22
// 181.207 us; speedup vs baseline: 1.3509x; 1.1258x over previous
//
#include <hip/hip_runtime.h>

// k-th NN distance (k=32 -> 33rd smallest, self excluded), B=16384, D=128.
// R22: k_gram loop reverted to R18 verbatim (verified 128.7us; R19/R20/R21
// overlap attempts all regressed: spill, spill, ILP loss). k_thresh folded
// into k_gram's prologue (per-block partial-reduce + own-strip tacc in LDS,
// overlapped with tile-0 staging) — one fewer launch. prepstats/select/
// fallback unchanged (R18-verified).

typedef unsigned short u16;
typedef unsigned int   u32;
typedef __attribute__((ext_vector_type(8))) u16    ushort8;
typedef __attribute__((ext_vector_type(8))) __bf16 bf16x8;
typedef __attribute__((ext_vector_type(4))) float  f32x4;
typedef __attribute__((ext_vector_type(4))) u32    u32x4;

#define NB   16384
#define ND   128
#define NSEG 32           // segments per row = 4 q * 2 wc * 4 lq
#define SCAP 12           // slots per segment (lambda~2.25)
#define NTH  33           // 33rd smallest
#define ZWH  (-2.62f)     // WH quantile z: p~0.0044 -> ~72 cands/row
#define NEGF (-3.0e38f)
#define POSF ( 3.0e38f)
#define NPB  64           // rows per prepstats block
#define NPBL 256          // prepstats grid

// ---- workspace layout (bytes), total ~31.5 MB ----
#define OFF_X    ((size_t)0)
#define OFF_NORM (OFF_X    + (size_t)NB * ND * 2)
#define OFF_PART (OFF_NORM + (size_t)NB * 4)
#define OFF_CNTS (OFF_PART + (size_t)NPBL * 130 * 4)
#define OFF_CAND (OFF_CNTS + (size_t)NB * NSEG * 4)

static __device__ __forceinline__ u16 f2bf(float f) {
  u32 u = __float_as_uint(f);
  u32 r = u + 0x7FFFu + ((u >> 16) & 1u);
  return (u16)(r >> 16);
}
static __device__ __forceinline__ float bf2f(u16 h) {
  return __uint_as_float(((u32)h) << 16);
}

#if defined(__has_builtin)
#if __has_builtin(__builtin_amdgcn_global_load_lds)
#define HAVE_GLDS 1
#endif
#endif

// Stage 16B/lane: LDS dest = wave-uniform base + lane*16 (linear).
static __device__ __forceinline__ void stage16(const u16* gsrc_lane,
                                               u16* lds_base, int l) {
#ifdef HAVE_GLDS
  __builtin_amdgcn_global_load_lds(
      (const __attribute__((address_space(1))) void*)gsrc_lane,
      (__attribute__((address_space(3))) void*)lds_base, 16, 0, 0);
#else
  *(ushort8*)(lds_base + l * 8) = *(const ushort8*)gsrc_lane;
#endif
}
// Stage 4B/lane (for the column-norm vector).
static __device__ __forceinline__ void stage4(const float* gsrc_lane,
                                              float* lds_base, int l) {
#ifdef HAVE_GLDS
  __builtin_amdgcn_global_load_lds(
      (const __attribute__((address_space(1))) void*)gsrc_lane,
      (__attribute__((address_space(3))) void*)lds_base, 4, 0, 0);
#else
  lds_base[l] = *gsrc_lane;
#endif
}

// ---------------- K1: fused bf16 convert + norms + stat partials ---------
__global__ void k_prepstats(const float* __restrict__ x, u16* __restrict__ X,
                            float* __restrict__ norms, float* __restrict__ partial) {
  __shared__ float xs[16][128];
  __shared__ float red1[256], red2[256];
  int t = threadIdx.x;
  int cg = t & 15;          // col-group: cols cg*8 .. cg*8+7
  int rs = t >> 4;          // row-sub 0..15
  int rbase = blockIdx.x * NPB;
  float cs[8] = {0.f, 0.f, 0.f, 0.f, 0.f, 0.f, 0.f, 0.f};
  float s1 = 0.f, s2 = 0.f;
#pragma unroll
  for (int rr = 0; rr < NPB / 16; ++rr) {
    int row = rbase + rs + rr * 16;
    const float* src = x + (size_t)row * ND + cg * 8;
    float4 a0 = *(const float4*)(src);
    float4 a1 = *(const float4*)(src + 4);
    float v[8] = {a0.x, a0.y, a0.z, a0.w, a1.x, a1.y, a1.z, a1.w};
    ushort8 pack;
    float ns = 0.f;
#pragma unroll
    for (int u = 0; u < 8; ++u) {
      u16 h = f2bf(v[u]);
      float b = bf2f(h);
      pack[u] = h;
      ns += b * b;
      cs[u] += b;
    }
    *(ushort8*)(X + (size_t)row * ND + cg * 8) = pack;
#pragma unroll
    for (int off = 1; off < 16; off <<= 1) ns += __shfl_xor(ns, off, 64);
    if (cg == 0) { norms[row] = ns; s1 += ns; s2 += ns * ns; }
  }
#pragma unroll
  for (int u = 0; u < 8; ++u) xs[rs][cg * 8 + u] = cs[u];
  red1[t] = s1; red2[t] = s2;
  __syncthreads();
  if (t < 128) {
    float a = 0.f;
    for (int r2 = 0; r2 < 16; ++r2) a += xs[r2][t];
    partial[(size_t)blockIdx.x * 130 + t] = a;
  }
  for (int st = 128; st > 0; st >>= 1) {
    if (t < st) { red1[t] += red1[t + st]; red2[t] += red2[t + st]; }
    __syncthreads();
  }
  if (t == 0) {
    partial[(size_t)blockIdx.x * 130 + 128] = red1[0];
    partial[(size_t)blockIdx.x * 130 + 129] = red2[0];
  }
}

// ---------------- K2: MFMA gram (R18 loop verbatim) + inline thresh ------
// 512 blocks = 128 strips x 4 quarters (XCD-chunked). 8 waves (512 thr):
// (wr=w>>1) x (wc=w&1); wave = 32 rows x 64 cols of the 128x128 iter tile.
// Prologue: reduce stat partials + compute this strip's tacc into LDS
// (overlapped with tile-0 staging). Loop identical to R18 (verified).
__global__ __launch_bounds__(512, 4) void k_gram(
    const u16* __restrict__ X, const float* __restrict__ norms,
    const float* __restrict__ partial, u32* __restrict__ counts,
    float* __restrict__ cands) {
  __shared__ u16 ldsA[2][32 * 512];            // 2 x 32KB
  __shared__ __align__(16) float nchs[2][128];
  __shared__ float xb[128];
  __shared__ float ssum[2];
  __shared__ float taccL[128];
  const int bid = blockIdx.x;
  const int logical = (bid & 7) * 64 + (bid >> 3);   // XCD-chunked, bijective
  const int q = logical >> 7, strip = logical & 127;
  const int r0 = strip * 128;
  const int t = threadIdx.x, w = t >> 6, l = t & 63;
  const int wr = w >> 1, wc = w & 1;
  const int lm = l & 15, lq = l >> 4;
  const int koff = lq * 8;

  // stage tile 0 first (latency overlaps the threshold prologue below)
  {
    const int c0 = q * 4096;
#pragma unroll
    for (int s = 0; s < 4; ++s) {
      int g = w * 4 + s;                 // e16 = g&7, k-chunk = g>>3
      stage16(X + (size_t)(c0 + (g & 7) * 16 + lm) * ND + (g >> 3) * 32 + koff,
              &ldsA[0][g * 512], l);
    }
    if (w < 2) stage4(norms + c0 + w * 64 + l, &nchs[0][w * 64], l);
  }

  // threshold prologue: reduce 256 partials -> xb, ssum
  if (t < 130) {
    float a = 0.f;
    for (int b = 0; b < NPBL; ++b) a += partial[(size_t)b * 130 + t];
    if (t < 128) xb[t] = a * (1.0f / NB);
    else         ssum[t - 128] = a;
  }
  __syncthreads();
  // per-row tacc for this strip (threads 0..127; X rows are L2-hit)
  if (t < 128) {
    int r = r0 + t;
    float n = norms[r];
    const u16* xr = X + (size_t)r * ND;
    float dot = 0.f;
#pragma unroll
    for (int c8 = 0; c8 < 16; ++c8) {
      ushort8 v = *(const ushort8*)(xr + c8 * 8);
#pragma unroll
      for (int j = 0; j < 8; ++j) dot += bf2f(v[j]) * xb[c8 * 8 + j];
    }
    float nbar = ssum[0] * (1.0f / NB);
    float Vn = fmaxf(ssum[1] * (1.0f / NB) - nbar * nbar, 0.f);
    float m = n + nbar - 2.f * dot;           // exact E_j[sq_rj]
    float v = Vn + 4.f * n * (nbar / ND);     // Var_j[sq_rj] model
    float nu = 2.f * m * m / v;
    float cc = v / (2.f * m);
    float a1 = 2.f / (9.f * nu);
    float inner = 1.f - a1 + ZWH * sqrtf(a1);
    float tsq = cc * nu * inner * inner * inner;
    taccL[t] = 0.5f * (n - tsq);  // val = acc - nc/2 >= tacc <=> sq <= tsq
  }
  __syncthreads();

  // B fragments (wave's 32 rows) -> registers, loaded once.
  bf16x8 bfrag[4][2];  // [k][j]
#pragma unroll
  for (int k = 0; k < 4; ++k)
#pragma unroll
    for (int j = 0; j < 2; ++j)
      bfrag[k][j] = __builtin_bit_cast(bf16x8, *(const ushort8*)(
          X + (size_t)(r0 + wr * 32 + j * 16 + lm) * ND + k * 32 + koff));

  int rj[2]; float tj[2]; u32 cnt2[2]; u32 segb[2];
#pragma unroll
  for (int j = 0; j < 2; ++j) {
    rj[j] = r0 + wr * 32 + j * 16 + lm;
    tj[j] = taccL[wr * 32 + j * 16 + lm];
    cnt2[j] = 0;
    segb[j] = (u32)(rj[j] * NSEG + q * 8 + wc * 4 + lq) * SCAP;
  }

  for (int it = 0; it < 32; ++it) {
    const int cur = it & 1;
    const int c0 = q * 4096 + it * 128;
    // issue next-tile staging FIRST (into the other buffer)
    if (it + 1 < 32) {
      const int c1 = c0 + 128;
      u16* dstA = ldsA[cur ^ 1];
#pragma unroll
      for (int s = 0; s < 4; ++s) {
        int g = w * 4 + s;
        stage16(X + (size_t)(c1 + (g & 7) * 16 + lm) * ND + (g >> 3) * 32 + koff,
                &dstA[g * 512], l);
      }
      if (w < 2) stage4(norms + c1 + w * 64 + l, &nchs[cur ^ 1][w * 64], l);
    }
    __builtin_amdgcn_sched_barrier(0);  // pin staging issue before compute

    f32x4 acc[4][2];
#pragma unroll
    for (int i = 0; i < 4; ++i)
#pragma unroll
      for (int j = 0; j < 2; ++j) acc[i][j] = (f32x4){0.f, 0.f, 0.f, 0.f};

    const u16* srcA = ldsA[cur];
#pragma unroll
    for (int k = 0; k < 4; ++k) {
      bf16x8 af[4];
#pragma unroll
      for (int i = 0; i < 4; ++i)
        af[i] = __builtin_bit_cast(bf16x8,
                 *(const ushort8*)(&srcA[(k * 8 + wc * 4 + i) * 512 + l * 8]));
#pragma unroll
      for (int i = 0; i < 4; ++i)
#pragma unroll
        for (int j = 0; j < 2; ++j)
          acc[i][j] = __builtin_amdgcn_mfma_f32_16x16x32_bf16(af[i], bfrag[k][j], acc[i][j], 0, 0, 0);
    }

    f32x4 nch4[4];
#pragma unroll
    for (int i = 0; i < 4; ++i) {
      nch4[i] = *(const f32x4*)(&nchs[cur][wc * 64 + i * 16 + lq * 4]);
      nch4[i] = nch4[i] * 0.5f;
    }

    // per-value predicated filter (R5/R18-verified form)
    const bool dg = (c0 == r0);
#pragma unroll
    for (int i = 0; i < 4; ++i) {
#pragma unroll
      for (int j = 0; j < 2; ++j) {
#pragma unroll
        for (int v = 0; v < 4; ++v) {
          float val = acc[i][j][v] - nch4[i][v];   // = x_c.x_r - n_c/2
          bool p = (val >= tj[j]);
          if (dg) p = p && ((c0 + wc * 64 + i * 16 + lq * 4 + v) != rj[j]);
          if (p) {
            u32 c = cnt2[j];
            if (c < SCAP) cands[segb[j] + c] = val;
            cnt2[j] = c + 1;   // count past cap -> overflow detect
          }
        }
      }
    }

    __syncthreads();  // drains vmcnt(0): next tile staged; cur readers done
  }
#pragma unroll
  for (int j = 0; j < 2; ++j)
    counts[rj[j] * NSEG + q * 8 + wc * 4 + lq] = cnt2[j];
}

// ---------------- K3: per-row exact 33rd smallest among candidates --------
__global__ void k_select(const u32* __restrict__ counts, const float* __restrict__ cands,
                         const float* __restrict__ norms, float* __restrict__ out) {
  int w = threadIdx.x >> 6, l = threadIdx.x & 63;
  int r = blockIdx.x * 4 + w;  // grid 4096
  u32 myc = (l < NSEG) ? counts[r * NSEG + l] : 0u;
  u32 tot = myc, mx = myc;
#pragma unroll
  for (int off = 1; off < 64; off <<= 1) {
    tot += __shfl_xor(tot, off, 64);
    u32 o = (u32)__shfl_xor((int)mx, off, 64);
    mx = mx > o ? mx : o;
  }
  if (tot < NTH || mx > SCAP) return;  // fallback kernel owns this row

  const float* base = cands + (size_t)r * (NSEG * SCAP);
  float v0, v1, v2, v3, v4, v5;
#define LOADV(e, dst)                                        \
  {                                                          \
    int f = l + 64 * e;                                      \
    int sg = f / SCAP, sl = f - sg * SCAP;                   \
    u32 c = (u32)__shfl((int)myc, sg, 64);                   \
    float x = base[f];                                       \
    dst = (sl < (int)c) ? x : NEGF;                          \
  }
  LOADV(0, v0) LOADV(1, v1) LOADV(2, v2) LOADV(3, v3) LOADV(4, v4) LOADV(5, v5)
#undef LOADV

  float last = NEGF;
  for (int e = 0; e < NTH; ++e) {  // bigger val = closer; extract-max x33
    float m = fmaxf(fmaxf(fmaxf(v0, v1), fmaxf(v2, v3)), fmaxf(v4, v5));
#pragma unroll
    for (int off = 1; off < 64; off <<= 1) m = fmaxf(m, __shfl_xor(m, off, 64));
    bool mine = (v0 == m) || (v1 == m) || (v2 == m) || (v3 == m) || (v4 == m) || (v5 == m);
    unsigned long long bal = __ballot(mine);
    int owner = __ffsll(bal) - 1;
    if (l == owner) {
      if      (v0 == m) v0 = NEGF;
      else if (v1 == m) v1 = NEGF;
      else if (v2 == m) v2 = NEGF;
      else if (v3 == m) v3 = NEGF;
      else if (v4 == m) v4 = NEGF;
      else              v5 = NEGF;
    }
    last = m;
  }
  out[r] = sqrtf(fmaxf(norms[r] - 2.f * last, 0.f));  // sq = n_r - 2*val
}

// ---------------- K4: exact brute-force fallback (expected ~0 rows) -------
__global__ void k_fallback(const u32* __restrict__ counts, const u16* __restrict__ X,
                           const float* __restrict__ norms, float* __restrict__ out) {
  __shared__ float sq[NB];     // 64 KB
  __shared__ float xr[ND];
  __shared__ float rmin[256];
  __shared__ int   ridx[256];
  __shared__ float tmin[256];
  __shared__ int   tidx[256];
  __shared__ int   nbad;
  __shared__ int   badlist[256];
  int t = threadIdx.x;
  if (t == 0) nbad = 0;
  __syncthreads();
  int r = blockIdx.x * 256 + t;   // grid 64: covers NB exactly
  u32 tot = 0, mx = 0;
#pragma unroll
  for (int s4 = 0; s4 < 8; ++s4) {
    u32x4 c = *(const u32x4*)(counts + (size_t)r * NSEG + s4 * 4);
#pragma unroll
    for (int u = 0; u < 4; ++u) { tot += c[u]; mx = c[u] > mx ? c[u] : mx; }
  }
  if (tot < NTH || mx > SCAP) { int p = atomicAdd(&nbad, 1); badlist[p] = r; }
  __syncthreads();
  int nb = nbad;
  for (int ii = 0; ii < nb; ++ii) {
    int rr = badlist[ii];
    if (t < 128) xr[t] = bf2f(X[(size_t)rr * ND + t]);
    __syncthreads();
    float n_r = norms[rr];
    for (int jj = 0; jj < 64; ++jj) {
      int j = t + 256 * jj;
      const u16* xj = X + (size_t)j * ND;
      float dot = 0.f;
#pragma unroll
      for (int c8 = 0; c8 < 16; ++c8) {
        ushort8 vv = *(const ushort8*)(xj + c8 * 8);
#pragma unroll
        for (int u = 0; u < 8; ++u) dot += bf2f(vv[u]) * xr[c8 * 8 + u];
      }
      sq[j] = (j == rr) ? POSF : fmaxf(n_r + norms[j] - 2.f * dot, 0.f);
    }
    __syncthreads();
    {
      float lmv = POSF; int lix = -1;
      for (int jj = 0; jj < 64; ++jj) {
        int j = t + 256 * jj;
        float s = sq[j];
        if (s < lmv) { lmv = s; lix = j; }
      }
      rmin[t] = lmv; ridx[t] = lix;
    }
    __syncthreads();
    float last = 0.f;
    for (int e = 0; e < NTH; ++e) {
      tmin[t] = rmin[t]; tidx[t] = ridx[t];
      __syncthreads();
      for (int s = 128; s > 0; s >>= 1) {
        if (t < s && tmin[t + s] < tmin[t]) { tmin[t] = tmin[t + s]; tidx[t] = tidx[t + s]; }
        __syncthreads();
      }
      float gm = tmin[0]; int gi = tidx[0];
      last = gm;
      __syncthreads();
      if (t == (gi & 255)) {         // owner clears and rescans its stripe
        sq[gi] = POSF;
        float lmv = POSF; int lix = -1;
        for (int jj = 0; jj < 64; ++jj) {
          int j = t + 256 * jj;
          float s = sq[j];
          if (s < lmv) { lmv = s; lix = j; }
        }
        rmin[t] = lmv; ridx[t] = lix;
      }
      __syncthreads();
    }
    if (t == 0) out[rr] = sqrtf(fmaxf(last, 0.f));
    __syncthreads();
  }
}

extern "C" void kernel_launch(void* const* d_in, const int* in_sizes, int n_in,
                              void* d_out, int out_size, void* d_ws, size_t ws_size,
                              hipStream_t stream) {
  const float* x = (const float*)d_in[0];
  float* out = (float*)d_out;
  char* ws = (char*)d_ws;
  u16*   X     = (u16*)  (ws + OFF_X);
  float* norms = (float*)(ws + OFF_NORM);
  float* part  = (float*)(ws + OFF_PART);
  u32*   cnts  = (u32*)  (ws + OFF_CNTS);
  float* cands = (float*)(ws + OFF_CAND);

  k_prepstats<<<NPBL, 256, 0, stream>>>(x, X, norms, part);
  k_gram     <<<512,  512, 0, stream>>>(X, norms, part, cnts, cands);
  k_select   <<<4096, 256, 0, stream>>>(cnts, cands, norms, out);
  k_fallback <<<64,   256, 0, stream>>>(cnts, X, norms, out);
}